// Round 1
// baseline (24273.450 us; speedup 1.0000x reference)
//
#include <hip/hip_runtime.h>

#define H 128

// ---------------- scatter: agg[dst] += xs[src]; cnt[dst] += 1 ----------------
__global__ void scatter_kernel(const float* __restrict__ xs,
                               const int* __restrict__ src,
                               const int* __restrict__ dst,
                               float* __restrict__ agg,
                               float* __restrict__ cnt,
                               long E) {
    long nitems = E * 32;  // (edge, float4-of-feature)
    long stride = (long)gridDim.x * blockDim.x;
    for (long i = (long)blockIdx.x * blockDim.x + threadIdx.x; i < nitems; i += stride) {
        long e = i >> 5;
        int f4 = (int)(i & 31);
        int s = src[e];
        int d = dst[e];
        const float4 v = *reinterpret_cast<const float4*>(xs + (long)s * H + f4 * 4);
        float* b = agg + (long)d * H + f4 * 4;
        atomicAdd(b + 0, v.x);
        atomicAdd(b + 1, v.y);
        atomicAdd(b + 2, v.z);
        atomicAdd(b + 3, v.w);
        if (f4 == 0) atomicAdd(cnt + d, 1.0f);
    }
}

// ---------------- wsum: sum Wr / bl over a relation range ----------------
__global__ void wsum_kernel(const float* __restrict__ Wr, const float* __restrict__ bl,
                            float* __restrict__ wsum, float* __restrict__ bsum,
                            int l, int r0, int nrel) {
    int i = blockIdx.x * blockDim.x + threadIdx.x;  // 0..16383
    float s = 0.f;
    for (int r = 0; r < nrel; ++r) s += Wr[(long)((l * 5) + r0 + r) * (H * H) + i];
    wsum[i] = s;
    if (i < H) {
        float b = 0.f;
        for (int r = 0; r < nrel; ++r) b += bl[(long)((l * 5) + r0 + r) * H + i];
        bsum[i] = b;
    }
}

// ---------------- GEMM: Y (+)= (A/cnt) @ W (+ bias) ----------------
// Tile: 128 rows x 128 cols, 256 threads (16x16), 8x8 per thread (split rows/cols).
// K staged in halves of 64 to keep LDS at 64KB (2 blocks/CU).
__global__ __launch_bounds__(256) void gemm_kernel(
    const float* __restrict__ A, const float* __restrict__ cnt,
    const float* __restrict__ W, const float* __restrict__ bias,
    float* __restrict__ Y, int M, int mode /*0: Y=acc+bias, 1: Y+=acc*/) {
    __shared__ float Wh[64 * 128];  // 32 KB, [k_local][n]
    __shared__ float At[64 * 128];  // 32 KB, [k_local][r] (transposed A chunk)

    const int t = threadIdx.x;
    const int tc = t & 15;   // 0..15
    const int tr = t >> 4;   // 0..15
    const long base = (long)blockIdx.x * 128;
    const int rows = (int)((M - base) < 128 ? (M - base) : 128);

    float acc[8][8];
#pragma unroll
    for (int i = 0; i < 8; ++i)
#pragma unroll
        for (int j = 0; j < 8; ++j) acc[i][j] = 0.f;

    for (int kh = 0; kh < 128; kh += 64) {
        __syncthreads();
        // stage W half: 64x128 = 2048 float4, 8 per thread (coalesced)
#pragma unroll
        for (int j = 0; j < 8; ++j) {
            int f = j * 256 + t;    // 0..2047
            int kk = f >> 5;        // 0..63
            int n4 = f & 31;
            *reinterpret_cast<float4*>(&Wh[kk * 128 + n4 * 4]) =
                *reinterpret_cast<const float4*>(&W[(long)(kh + kk) * H + n4 * 4]);
        }
        // stage A^T half with optional 1/cnt scaling
#pragma unroll
        for (int j = 0; j < 8; ++j) {
            int f = j * 256 + t;    // 0..2047
            int r = f & 127;
            int k4 = f >> 7;        // 0..15
            float4 v = make_float4(0.f, 0.f, 0.f, 0.f);
            float sc = 0.f;
            if (r < rows) {
                v = *reinterpret_cast<const float4*>(&A[(base + r) * H + kh + k4 * 4]);
                sc = 1.0f;
                if (cnt) sc = 1.0f / fmaxf(cnt[base + r], 1.0f);
            }
            At[(k4 * 4 + 0) * 128 + r] = v.x * sc;
            At[(k4 * 4 + 1) * 128 + r] = v.y * sc;
            At[(k4 * 4 + 2) * 128 + r] = v.z * sc;
            At[(k4 * 4 + 3) * 128 + r] = v.w * sc;
        }
        __syncthreads();

#pragma unroll 8
        for (int k = 0; k < 64; ++k) {
            const float4 a0 = *reinterpret_cast<const float4*>(&At[k * 128 + tr * 4]);
            const float4 a1 = *reinterpret_cast<const float4*>(&At[k * 128 + 64 + tr * 4]);
            const float4 w0 = *reinterpret_cast<const float4*>(&Wh[k * 128 + tc * 4]);
            const float4 w1 = *reinterpret_cast<const float4*>(&Wh[k * 128 + 64 + tc * 4]);
            float av[8] = {a0.x, a0.y, a0.z, a0.w, a1.x, a1.y, a1.z, a1.w};
            float wv[8] = {w0.x, w0.y, w0.z, w0.w, w1.x, w1.y, w1.z, w1.w};
#pragma unroll
            for (int i = 0; i < 8; ++i)
#pragma unroll
                for (int j = 0; j < 8; ++j) acc[i][j] += av[i] * wv[j];
        }
    }

    // epilogue
#pragma unroll
    for (int i = 0; i < 8; ++i) {
        int r = (i < 4) ? (tr * 4 + i) : (64 + tr * 4 + (i - 4));
        if (r < rows) {
#pragma unroll
            for (int g = 0; g < 2; ++g) {
                int c = g * 64 + tc * 4;
                float* yp = Y + (base + r) * H + c;
                float4 o;
                o.x = acc[i][g * 4 + 0];
                o.y = acc[i][g * 4 + 1];
                o.z = acc[i][g * 4 + 2];
                o.w = acc[i][g * 4 + 3];
                if (mode == 0) {
                    const float4 b = *reinterpret_cast<const float4*>(bias + c);
                    o.x += b.x; o.y += b.y; o.z += b.z; o.w += b.w;
                } else {
                    const float4 old = *reinterpret_cast<const float4*>(yp);
                    o.x += old.x; o.y += old.y; o.z += old.z; o.w += old.w;
                }
                *reinterpret_cast<float4*>(yp) = o;
            }
        }
    }
}

// ---------------- relu + scale: y = max(0, y*s) ----------------
__global__ void relu_scale_kernel(float* __restrict__ Y, long n4, float s) {
    long stride = (long)gridDim.x * blockDim.x;
    for (long i = (long)blockIdx.x * blockDim.x + threadIdx.x; i < n4; i += stride) {
        float4 v = reinterpret_cast<float4*>(Y)[i];
        v.x = fmaxf(v.x * s, 0.f);
        v.y = fmaxf(v.y * s, 0.f);
        v.z = fmaxf(v.z * s, 0.f);
        v.w = fmaxf(v.w * s, 0.f);
        reinterpret_cast<float4*>(Y)[i] = v;
    }
}

extern "C" void kernel_launch(void* const* d_in, const int* in_sizes, int n_in,
                              void* d_out, int out_size, void* d_ws, size_t ws_size,
                              hipStream_t stream) {
    const float* xp0 = (const float*)d_in[0];
    const float* xa0 = (const float*)d_in[1];
    const float* xv0 = (const float*)d_in[2];
    const float* Wl  = (const float*)d_in[3];
    const float* bl  = (const float*)d_in[4];
    const float* Wr  = (const float*)d_in[5];
    const int* ei_w  = (const int*)d_in[6];
    const int* ei_c  = (const int*)d_in[7];
    const int* ei_p  = (const int*)d_in[8];
    const int* ei_rw = (const int*)d_in[9];
    const int* ei_rp = (const int*)d_in[10];

    const long NP = 200000, NA = 100000, NV = 10000;
    const long EW = 2000000, EC = 2000000, EP = 200000;

    float* ws = (float*)d_ws;
    float* xp1 = ws;
    float* xa1 = xp1 + NP * H;
    float* xv1 = xa1 + NA * H;
    float* agg = xv1 + NV * H;
    float* cnt = agg + NP * H;
    float* wsum = cnt + NP;
    float* bsum = wsum + H * H;

    float* op = (float*)d_out;
    float* oa = op + NP * H;
    float* ov = oa + NA * H;

    const int SC_GRID = 2048, SC_BLK = 256;

    auto run_layer = [&](int l, const float* xp, const float* xa, const float* xv,
                         float* yp, float* ya, float* yv) {
        // ---- dst = paper (relations 0,1,2) ----
        wsum_kernel<<<64, 256, 0, stream>>>(Wr, bl, wsum, bsum, l, 0, 3);
        gemm_kernel<<<(int)((NP + 127) / 128), 256, 0, stream>>>(xp, nullptr, wsum, bsum, yp, (int)NP, 0);
        const float* srcs[3] = {xa, xp, xv};
        const int* eis[3] = {ei_w, ei_c, ei_p};
        const long Es[3] = {EW, EC, EP};
        for (int rr = 0; rr < 3; ++rr) {
            hipMemsetAsync(agg, 0, NP * H * sizeof(float), stream);
            hipMemsetAsync(cnt, 0, NP * sizeof(float), stream);
            scatter_kernel<<<SC_GRID, SC_BLK, 0, stream>>>(srcs[rr], eis[rr], eis[rr] + Es[rr],
                                                           agg, cnt, Es[rr]);
            gemm_kernel<<<(int)((NP + 127) / 128), 256, 0, stream>>>(
                agg, cnt, Wl + (long)((l * 5) + rr) * H * H, nullptr, yp, (int)NP, 1);
        }
        relu_scale_kernel<<<2048, 256, 0, stream>>>(yp, NP * H / 4, 1.0f / 3.0f);

        // ---- dst = author (relation 3: rev_writes, src = paper) ----
        gemm_kernel<<<(int)((NA + 127) / 128), 256, 0, stream>>>(
            xa, nullptr, Wr + (long)((l * 5) + 3) * H * H, bl + (long)((l * 5) + 3) * H, ya, (int)NA, 0);
        hipMemsetAsync(agg, 0, NA * H * sizeof(float), stream);
        hipMemsetAsync(cnt, 0, NA * sizeof(float), stream);
        scatter_kernel<<<SC_GRID, SC_BLK, 0, stream>>>(xp, ei_rw, ei_rw + EW, agg, cnt, EW);
        gemm_kernel<<<(int)((NA + 127) / 128), 256, 0, stream>>>(
            agg, cnt, Wl + (long)((l * 5) + 3) * H * H, nullptr, ya, (int)NA, 1);
        relu_scale_kernel<<<2048, 256, 0, stream>>>(ya, NA * H / 4, 1.0f);

        // ---- dst = venue (relation 4: rev_publishes, src = paper) ----
        gemm_kernel<<<(int)((NV + 127) / 128), 256, 0, stream>>>(
            xv, nullptr, Wr + (long)((l * 5) + 4) * H * H, bl + (long)((l * 5) + 4) * H, yv, (int)NV, 0);
        hipMemsetAsync(agg, 0, NV * H * sizeof(float), stream);
        hipMemsetAsync(cnt, 0, NV * sizeof(float), stream);
        scatter_kernel<<<SC_GRID, SC_BLK, 0, stream>>>(xp, ei_rp, ei_rp + EP, agg, cnt, EP);
        gemm_kernel<<<(int)((NV + 127) / 128), 256, 0, stream>>>(
            agg, cnt, Wl + (long)((l * 5) + 4) * H * H, nullptr, yv, (int)NV, 1);
        relu_scale_kernel<<<2048, 256, 0, stream>>>(yv, NV * H / 4, 1.0f);
    };

    run_layer(0, xp0, xa0, xv0, xp1, xa1, xv1);
    run_layer(1, xp1, xa1, xv1, op, oa, ov);
}

// Round 2
// 3266.547 us; speedup vs baseline: 7.4309x; 7.4309x over previous
//
#include <hip/hip_runtime.h>

#define H 128

// ---------------- CSR build ----------------
__global__ void hist_kernel(const int* __restrict__ dst, int* __restrict__ deg, long E) {
    long stride = (long)gridDim.x * blockDim.x;
    for (long e = (long)blockIdx.x * blockDim.x + threadIdx.x; e < E; e += stride)
        atomicAdd(&deg[dst[e]], 1);
}

__global__ void scan_reduce(const int* __restrict__ deg, int* __restrict__ bsum, int n) {
    __shared__ int sdata[256];
    int b = blockIdx.x, t = threadIdx.x;
    int base = b * 1024;
    int s = 0;
#pragma unroll
    for (int j = 0; j < 4; ++j) {
        int i = base + t * 4 + j;
        if (i < n) s += deg[i];
    }
    sdata[t] = s;
    __syncthreads();
    for (int o = 128; o > 0; o >>= 1) {
        if (t < o) sdata[t] += sdata[t + o];
        __syncthreads();
    }
    if (t == 0) bsum[b] = sdata[0];
}

__global__ void scan_bsum(int* __restrict__ bsum, int nb) {
    if (threadIdx.x == 0 && blockIdx.x == 0) {
        int acc = 0;
        for (int i = 0; i < nb; ++i) {
            int v = bsum[i];
            bsum[i] = acc;
            acc += v;
        }
    }
}

__global__ void scan_final(const int* __restrict__ deg, const int* __restrict__ bsum,
                           int* __restrict__ row_ptr, int n, int E) {
    __shared__ int ssum[256];
    int b = blockIdx.x, t = threadIdx.x;
    int base = b * 1024;
    int v[4];
    int s = 0;
#pragma unroll
    for (int j = 0; j < 4; ++j) {
        int i = base + t * 4 + j;
        v[j] = (i < n) ? deg[i] : 0;
        s += v[j];
    }
    ssum[t] = s;
    __syncthreads();
    for (int o = 1; o < 256; o <<= 1) {
        int x = (t >= o) ? ssum[t - o] : 0;
        __syncthreads();
        ssum[t] += x;
        __syncthreads();
    }
    int excl = bsum[b] + ((t > 0) ? ssum[t - 1] : 0);
#pragma unroll
    for (int j = 0; j < 4; ++j) {
        int i = base + t * 4 + j;
        if (i < n) {
            row_ptr[i] = excl;
            excl += v[j];
        }
    }
    if (b == 0 && t == 0) row_ptr[n] = E;
}

__global__ void fill_kernel(const int* __restrict__ src, const int* __restrict__ dst,
                            const int* __restrict__ row_ptr, int* __restrict__ cursor,
                            int* __restrict__ out_src, long E) {
    long stride = (long)gridDim.x * blockDim.x;
    for (long e = (long)blockIdx.x * blockDim.x + threadIdx.x; e < E; e += stride) {
        int d = dst[e];
        int pos = atomicAdd(&cursor[d], 1);
        out_src[row_ptr[d] + pos] = src[e];
    }
}

// ---------------- gather mean: one wave per dst row ----------------
__global__ void gather_mean_kernel(const float* __restrict__ xs,
                                   const int* __restrict__ row_ptr,
                                   const int* __restrict__ srcs,
                                   float* __restrict__ out, int n_dst) {
    long gid = (long)blockIdx.x * blockDim.x + threadIdx.x;
    int w = (int)(gid >> 6);
    int lane = (int)(gid & 63);
    if (w >= n_dst) return;
    int beg = row_ptr[w], end = row_ptr[w + 1];
    float ax = 0.f, ay = 0.f;
    int j = beg;
    for (; j + 1 < end; j += 2) {
        int s0 = srcs[j], s1 = srcs[j + 1];
        float2 v0 = *reinterpret_cast<const float2*>(xs + (long)s0 * H + lane * 2);
        float2 v1 = *reinterpret_cast<const float2*>(xs + (long)s1 * H + lane * 2);
        ax += v0.x + v1.x;
        ay += v0.y + v1.y;
    }
    if (j < end) {
        int s0 = srcs[j];
        float2 v0 = *reinterpret_cast<const float2*>(xs + (long)s0 * H + lane * 2);
        ax += v0.x;
        ay += v0.y;
    }
    float inv = 1.0f / fmaxf((float)(end - beg), 1.0f);
    *reinterpret_cast<float2*>(out + (long)w * H + lane * 2) = make_float2(ax * inv, ay * inv);
}

// ---------------- wsum: sum Wr / bl over a relation range ----------------
__global__ void wsum_kernel(const float* __restrict__ Wr, const float* __restrict__ bl,
                            float* __restrict__ wsum, float* __restrict__ bsum,
                            int l, int r0, int nrel) {
    int i = blockIdx.x * blockDim.x + threadIdx.x;  // 0..16383
    float s = 0.f;
    for (int r = 0; r < nrel; ++r) s += Wr[(long)((l * 5) + r0 + r) * (H * H) + i];
    wsum[i] = s;
    if (i < H) {
        float b = 0.f;
        for (int r = 0; r < nrel; ++r) b += bl[(long)((l * 5) + r0 + r) * H + i];
        bsum[i] = b;
    }
}

// ---------------- GEMM: Y (+)= A @ W (+ bias) ----------------
__global__ __launch_bounds__(256) void gemm_kernel(
    const float* __restrict__ A,
    const float* __restrict__ W, const float* __restrict__ bias,
    float* __restrict__ Y, int M, int mode /*0: Y=acc+bias, 1: Y+=acc*/) {
    __shared__ float Wh[64 * 128];  // 32 KB, [k_local][n]
    __shared__ float At[64 * 128];  // 32 KB, [k_local][r]

    const int t = threadIdx.x;
    const int tc = t & 15;
    const int tr = t >> 4;
    const long base = (long)blockIdx.x * 128;
    const int rows = (int)((M - base) < 128 ? (M - base) : 128);

    float acc[8][8];
#pragma unroll
    for (int i = 0; i < 8; ++i)
#pragma unroll
        for (int j = 0; j < 8; ++j) acc[i][j] = 0.f;

    for (int kh = 0; kh < 128; kh += 64) {
        __syncthreads();
#pragma unroll
        for (int j = 0; j < 8; ++j) {
            int f = j * 256 + t;
            int kk = f >> 5;
            int n4 = f & 31;
            *reinterpret_cast<float4*>(&Wh[kk * 128 + n4 * 4]) =
                *reinterpret_cast<const float4*>(&W[(long)(kh + kk) * H + n4 * 4]);
        }
#pragma unroll
        for (int j = 0; j < 8; ++j) {
            int f = j * 256 + t;
            int r = f & 127;
            int k4 = f >> 7;
            float4 v = make_float4(0.f, 0.f, 0.f, 0.f);
            if (r < rows)
                v = *reinterpret_cast<const float4*>(&A[(base + r) * H + kh + k4 * 4]);
            At[(k4 * 4 + 0) * 128 + r] = v.x;
            At[(k4 * 4 + 1) * 128 + r] = v.y;
            At[(k4 * 4 + 2) * 128 + r] = v.z;
            At[(k4 * 4 + 3) * 128 + r] = v.w;
        }
        __syncthreads();

#pragma unroll 8
        for (int k = 0; k < 64; ++k) {
            const float4 a0 = *reinterpret_cast<const float4*>(&At[k * 128 + tr * 4]);
            const float4 a1 = *reinterpret_cast<const float4*>(&At[k * 128 + 64 + tr * 4]);
            const float4 w0 = *reinterpret_cast<const float4*>(&Wh[k * 128 + tc * 4]);
            const float4 w1 = *reinterpret_cast<const float4*>(&Wh[k * 128 + 64 + tc * 4]);
            float av[8] = {a0.x, a0.y, a0.z, a0.w, a1.x, a1.y, a1.z, a1.w};
            float wv[8] = {w0.x, w0.y, w0.z, w0.w, w1.x, w1.y, w1.z, w1.w};
#pragma unroll
            for (int i = 0; i < 8; ++i)
#pragma unroll
                for (int j = 0; j < 8; ++j) acc[i][j] += av[i] * wv[j];
        }
    }

#pragma unroll
    for (int i = 0; i < 8; ++i) {
        int r = (i < 4) ? (tr * 4 + i) : (64 + tr * 4 + (i - 4));
        if (r < rows) {
#pragma unroll
            for (int g = 0; g < 2; ++g) {
                int c = g * 64 + tc * 4;
                float* yp = Y + (base + r) * H + c;
                float4 o;
                o.x = acc[i][g * 4 + 0];
                o.y = acc[i][g * 4 + 1];
                o.z = acc[i][g * 4 + 2];
                o.w = acc[i][g * 4 + 3];
                if (mode == 0) {
                    const float4 b = *reinterpret_cast<const float4*>(bias + c);
                    o.x += b.x; o.y += b.y; o.z += b.z; o.w += b.w;
                } else {
                    const float4 old = *reinterpret_cast<const float4*>(yp);
                    o.x += old.x; o.y += old.y; o.z += old.z; o.w += old.w;
                }
                *reinterpret_cast<float4*>(yp) = o;
            }
        }
    }
}

// ---------------- relu + scale ----------------
__global__ void relu_scale_kernel(float* __restrict__ Y, long n4, float s) {
    long stride = (long)gridDim.x * blockDim.x;
    for (long i = (long)blockIdx.x * blockDim.x + threadIdx.x; i < n4; i += stride) {
        float4 v = reinterpret_cast<float4*>(Y)[i];
        v.x = fmaxf(v.x * s, 0.f);
        v.y = fmaxf(v.y * s, 0.f);
        v.z = fmaxf(v.z * s, 0.f);
        v.w = fmaxf(v.w * s, 0.f);
        reinterpret_cast<float4*>(Y)[i] = v;
    }
}

extern "C" void kernel_launch(void* const* d_in, const int* in_sizes, int n_in,
                              void* d_out, int out_size, void* d_ws, size_t ws_size,
                              hipStream_t stream) {
    const float* xp0 = (const float*)d_in[0];
    const float* xa0 = (const float*)d_in[1];
    const float* xv0 = (const float*)d_in[2];
    const float* Wl  = (const float*)d_in[3];
    const float* bl  = (const float*)d_in[4];
    const float* Wr  = (const float*)d_in[5];
    const int* ei_w  = (const int*)d_in[6];
    const int* ei_c  = (const int*)d_in[7];
    const int* ei_p  = (const int*)d_in[8];
    const int* ei_rw = (const int*)d_in[9];
    const int* ei_rp = (const int*)d_in[10];

    const long NP = 200000, NA = 100000, NV = 10000;
    const long EW = 2000000, EC = 2000000, EP = 200000;

    float* ws = (float*)d_ws;
    float* xp1 = ws;
    float* xa1 = xp1 + NP * H;
    float* xv1 = xa1 + NA * H;
    float* agg = xv1 + NV * H;
    float* wsum = agg + NP * H;
    float* bsum = wsum + H * H;

    int* iw      = (int*)(bsum + H);
    int* rp_w    = iw;
    int* rp_c    = rp_w + (NP + 1);
    int* rp_p    = rp_c + (NP + 1);
    int* rp_rw   = rp_p + (NP + 1);
    int* rp_rp   = rp_rw + (NA + 1);
    int* srcs_w  = rp_rp + (NV + 1);
    int* srcs_c  = srcs_w + EW;
    int* srcs_p  = srcs_c + EC;
    int* srcs_rw = srcs_p + EP;
    int* srcs_rp = srcs_rw + EW;
    int* cursor  = srcs_rp + EP;
    int* bsums   = cursor + NP;

    float* op = (float*)d_out;
    float* oa = op + NP * H;
    float* ov = oa + NA * H;

    auto build_csr = [&](const int* ei, long E, int n_dst, int* rp, int* srcs) {
        hipMemsetAsync(cursor, 0, n_dst * sizeof(int), stream);
        hist_kernel<<<1024, 256, 0, stream>>>(ei + E, cursor, E);
        int nb = (n_dst + 1023) / 1024;
        scan_reduce<<<nb, 256, 0, stream>>>(cursor, bsums, n_dst);
        scan_bsum<<<1, 64, 0, stream>>>(bsums, nb);
        scan_final<<<nb, 256, 0, stream>>>(cursor, bsums, rp, n_dst, (int)E);
        hipMemsetAsync(cursor, 0, n_dst * sizeof(int), stream);
        fill_kernel<<<1024, 256, 0, stream>>>(ei, ei + E, rp, cursor, srcs, E);
    };

    build_csr(ei_w, EW, (int)NP, rp_w, srcs_w);
    build_csr(ei_c, EC, (int)NP, rp_c, srcs_c);
    build_csr(ei_p, EP, (int)NP, rp_p, srcs_p);
    build_csr(ei_rw, EW, (int)NA, rp_rw, srcs_rw);
    build_csr(ei_rp, EP, (int)NV, rp_rp, srcs_rp);

    auto run_layer = [&](int l, const float* xp, const float* xa, const float* xv,
                         float* yp, float* ya, float* yv) {
        // ---- dst = paper (relations 0,1,2) ----
        wsum_kernel<<<64, 256, 0, stream>>>(Wr, bl, wsum, bsum, l, 0, 3);
        gemm_kernel<<<(int)((NP + 127) / 128), 256, 0, stream>>>(xp, wsum, bsum, yp, (int)NP, 0);
        const float* srcs_x[3] = {xa, xp, xv};
        const int* rps[3] = {rp_w, rp_c, rp_p};
        int* sss[3] = {srcs_w, srcs_c, srcs_p};
        for (int rr = 0; rr < 3; ++rr) {
            gather_mean_kernel<<<(int)((NP * 64 + 255) / 256), 256, 0, stream>>>(
                srcs_x[rr], rps[rr], sss[rr], agg, (int)NP);
            gemm_kernel<<<(int)((NP + 127) / 128), 256, 0, stream>>>(
                agg, Wl + (long)((l * 5) + rr) * H * H, nullptr, yp, (int)NP, 1);
        }
        relu_scale_kernel<<<2048, 256, 0, stream>>>(yp, NP * H / 4, 1.0f / 3.0f);

        // ---- dst = author (relation 3: rev_writes, src = paper) ----
        gemm_kernel<<<(int)((NA + 127) / 128), 256, 0, stream>>>(
            xa, Wr + (long)((l * 5) + 3) * H * H, bl + (long)((l * 5) + 3) * H, ya, (int)NA, 0);
        gather_mean_kernel<<<(int)((NA * 64 + 255) / 256), 256, 0, stream>>>(
            xp, rp_rw, srcs_rw, agg, (int)NA);
        gemm_kernel<<<(int)((NA + 127) / 128), 256, 0, stream>>>(
            agg, Wl + (long)((l * 5) + 3) * H * H, nullptr, ya, (int)NA, 1);
        relu_scale_kernel<<<2048, 256, 0, stream>>>(ya, NA * H / 4, 1.0f);

        // ---- dst = venue (relation 4: rev_publishes, src = paper) ----
        gemm_kernel<<<(int)((NV + 127) / 128), 256, 0, stream>>>(
            xv, Wr + (long)((l * 5) + 4) * H * H, bl + (long)((l * 5) + 4) * H, yv, (int)NV, 0);
        gather_mean_kernel<<<(int)((NV * 64 + 255) / 256), 256, 0, stream>>>(
            xp, rp_rp, srcs_rp, agg, (int)NV);
        gemm_kernel<<<(int)((NV + 127) / 128), 256, 0, stream>>>(
            agg, Wl + (long)((l * 5) + 4) * H * H, nullptr, yv, (int)NV, 1);
        relu_scale_kernel<<<2048, 256, 0, stream>>>(yv, NV * H / 4, 1.0f);
    };

    run_layer(0, xp0, xa0, xv0, xp1, xa1, xv1);
    run_layer(1, xp1, xa1, xv1, op, oa, ov);
}